// Round 15
// baseline (170.441 us; speedup 1.0000x reference)
//
#include <hip/hip_runtime.h>
#include <hip/hip_bf16.h>

#define NTOT 8192
#define FIN 128
#define FOUT 32
#define NH 4
#define NSEG 4
#define SEGJ (NTOT / NSEG)  // 2048

typedef __attribute__((ext_vector_type(4))) float f32x4;
typedef __attribute__((ext_vector_type(4))) int i32x4;
typedef __attribute__((ext_vector_type(4))) unsigned int u32x4;
typedef __attribute__((ext_vector_type(8))) __bf16 bf16x8;
typedef unsigned long long u64;
typedef unsigned int u32;

__device__ __forceinline__ unsigned short f2bf(float x) {
  __hip_bfloat16 h = __float2bfloat16(x);
  return *reinterpret_cast<unsigned short*>(&h);
}

// ---------------- k1: h = X @ W -> h [N][128] f32, plus B-fragment panels:
// panel[(p*256 + jt)*512 + l*8 + e] (bf16), p = hd*2+half,
//   value = h[node = jt*32 + (l>>4)*8 + e][p*16 + (l&15)]
__global__ __launch_bounds__(256, 2) void k1_project(
    const float* __restrict__ X, const float* __restrict__ W,
    float* __restrict__ h, unsigned short* __restrict__ panel) {
  __shared__ float Xs[32 * 128];
  __shared__ float Ws[32 * 128];
  __shared__ unsigned short Hs[128 * 40];  // [o][node_local], stride 40
  int t = threadIdx.x;
  int nb = blockIdx.x * 32;

  const f32x4* Xg = reinterpret_cast<const f32x4*>(X + (size_t)nb * FIN);
  f32x4* Xs4 = reinterpret_cast<f32x4*>(Xs);
#pragma unroll
  for (int r = 0; r < 4; ++r) Xs4[t + r * 256] = Xg[t + r * 256];

  int ng = t >> 5, oq = t & 31;
  int n0 = ng * 4, o0 = oq * 4;
  f32x4 acc[4];
#pragma unroll
  for (int nn = 0; nn < 4; ++nn) acc[nn] = (f32x4){0.f, 0.f, 0.f, 0.f};

  for (int kp = 0; kp < 4; ++kp) {
    __syncthreads();
#pragma unroll
    for (int r = 0; r < 4; ++r) {
      int q = t + r * 256;
      int flat = q * 4;
      int kk = flat >> 7;
      int c = flat & 127;
      int hdd = c >> 5;
      int oo = c & 31;
      *reinterpret_cast<f32x4*>(&Ws[kk * 128 + c]) =
          *reinterpret_cast<const f32x4*>(W + hdd * (FIN * FOUT) +
                                          (kp * 32 + kk) * FOUT + oo);
    }
    __syncthreads();
#pragma unroll 8
    for (int kk = 0; kk < 32; ++kk) {
      f32x4 wv = *reinterpret_cast<const f32x4*>(&Ws[kk * 128 + o0]);
#pragma unroll
      for (int nn = 0; nn < 4; ++nn)
        acc[nn] += Xs[(n0 + nn) * 128 + kp * 32 + kk] * wv;
    }
  }
#pragma unroll
  for (int nn = 0; nn < 4; ++nn) {
    *reinterpret_cast<f32x4*>(&h[(size_t)(nb + n0 + nn) * 128 + o0]) = acc[nn];
#pragma unroll
    for (int c = 0; c < 4; ++c)
      Hs[(o0 + c) * 40 + (n0 + nn)] = f2bf(acc[nn][c]);
  }
  __syncthreads();
  int jt = blockIdx.x;
#pragma unroll
  for (int it = 0; it < 2; ++it) {
    int item = t + it * 256;
    int p = item >> 6;
    int l = item & 63;
    int o = p * 16 + (l & 15);
    u32x4 v = *reinterpret_cast<const u32x4*>(&Hs[o * 40 + (l >> 4) * 8]);
    *reinterpret_cast<u32x4*>(panel + (size_t)(p * 256 + jt) * 512 + l * 8) = v;
  }
}

// ---------------- k2: two-plane tables.
// Sf/E1f/E2f f32 [hd][N]; Dbf/F1bf/F2bf bf16 [jm][hd][64] (jm = j>>6)
__global__ __launch_bounds__(256, 2) void k2_scores(
    const float* __restrict__ h, const float* __restrict__ a_src,
    const float* __restrict__ a_dst, float* __restrict__ Sf,
    float* __restrict__ E1f, float* __restrict__ E2f,
    unsigned short* __restrict__ Dbf, unsigned short* __restrict__ F1bf,
    unsigned short* __restrict__ F2bf) {
  int n = blockIdx.x * 256 + threadIdx.x;
  const f32x4* hv = reinterpret_cast<const f32x4*>(h + (size_t)n * 128);
  const f32x4* as4 = reinterpret_cast<const f32x4*>(a_src);
  const f32x4* ad4 = reinterpret_cast<const f32x4*>(a_dst);
  int jm = n >> 6, jo = n & 63;
#pragma unroll
  for (int hd = 0; hd < NH; ++hd) {
    f32x4 sa = {0.f, 0.f, 0.f, 0.f}, da = {0.f, 0.f, 0.f, 0.f};
#pragma unroll
    for (int q = 0; q < 8; ++q) {
      f32x4 x = hv[hd * 8 + q];
      sa += x * as4[hd * 8 + q];
      da += x * ad4[hd * 8 + q];
    }
    float s = (sa[0] + sa[1]) + (sa[2] + sa[3]);
    float d = (da[0] + da[1]) + (da[2] + da[3]);
    Sf[hd * NTOT + n] = s;
    E1f[hd * NTOT + n] = expf(s);
    E2f[hd * NTOT + n] = expf(0.2f * s);
    int ti = (jm * 4 + hd) * 64 + jo;
    Dbf[ti] = f2bf(d);
    F1bf[ti] = f2bf(expf(d));
    F2bf[ti] = f2bf(expf(0.2f * d));
  }
}

// ---------------- k3: fused adj-read + two-plane masked-table softmax + PV.
// Wave = 16 rows x 2 heads. Block = 4 waves (2 rowhalf x 2 headpair) = 32 rows.
// Grid 1024 = 4096 waves = 4/SIMD. NO transcendentals / cvt in the hot loop:
// P = E1[i]*(mask_pos*F1[j]) + E2[i]*(mask_neg*F2[j]), E applied in epilogue.
__global__ __launch_bounds__(256)
__attribute__((amdgpu_waves_per_eu(2))) void k3_attn(
    const int* __restrict__ adj, const float* __restrict__ Sf,
    const float* __restrict__ E1f, const float* __restrict__ E2f,
    const unsigned short* __restrict__ Dbf,
    const unsigned short* __restrict__ F1bf,
    const unsigned short* __restrict__ F2bf,
    const unsigned short* __restrict__ panel, float* __restrict__ pacc,
    float* __restrict__ plsum) {
  const int N = NTOT;
  int tid = threadIdx.x;
  int w = tid >> 6, l = tid & 63;
  int rh = w & 1, hp = w >> 1;
  int itile = blockIdx.x >> 2, seg = blockIdx.x & 3;
  int ibase = itile * 32 + rh * 16;
  int m = l & 15, g = l >> 4, jc = g * 8;
  int row = ibase + m;
  int hd0 = hp * 2;

  float sv0 = Sf[hd0 * N + row];
  float sv1 = Sf[(hd0 + 1) * N + row];

  const int* adjr = adj + (size_t)row * N + seg * SEGJ + jc;
  const char* dB =
      (const char*)Dbf + (size_t)(seg * 32) * 512 + hd0 * 128 + jc * 2;
  const char* f1B =
      (const char*)F1bf + (size_t)(seg * 32) * 512 + hd0 * 128 + jc * 2;
  const char* f2B =
      (const char*)F2bf + (size_t)(seg * 32) * 512 + hd0 * 128 + jc * 2;
  const char* pB = (const char*)panel +
                   ((size_t)(hd0 * 2) * 256 + seg * 64) * 1024 + (size_t)l * 16;
  const size_t PS = (size_t)256 * 1024;  // panel plane stride (bytes)

  f32x4 z4 = {0.f, 0.f, 0.f, 0.f};
  f32x4 aP0[2] = {z4, z4}, aP1[2] = {z4, z4}, aPs[2] = {z4, z4};
  f32x4 aN0[2] = {z4, z4}, aN1[2] = {z4, z4}, aNs[2] = {z4, z4};
  bf16x8 bones;
  {
    u32 pat = (m == 0) ? 0x3f803f80u : 0u;
    u32x4 tmp = {pat, pat, pat, pat};
    bones = *reinterpret_cast<bf16x8*>(&tmp);
  }

#define MFM(AF, B, ACC) \
  ACC = __builtin_amdgcn_mfma_f32_16x16x32_bf16(AF, B, ACC, 0, 0, 0);

  // one AF (32 j) for one head: build masked two-plane frags + 6 MFMA
#define AFPLANE(HH, MK, Dv, F1v, F2v, B0, B1, SV)                         \
  {                                                                       \
    u32x4 aPw, aNw;                                                       \
    _Pragma("unroll") for (int p = 0; p < 4; ++p) {                       \
      float de = __uint_as_float(Dv[p] << 16);                            \
      float dodd = __uint_as_float(Dv[p] & 0xFFFF0000u);                  \
      u32 n0 = (u32)(__float_as_int((SV) + de) >> 31);                    \
      u32 n1 = (u32)(__float_as_int((SV) + dodd) >> 31);                  \
      u32 mn = __builtin_amdgcn_perm(n1, n0, 0x05040100u);                \
      aPw[p] = F1v[p] & ((MK)[p] & ~mn);                                  \
      aNw[p] = F2v[p] & ((MK)[p] & mn);                                   \
    }                                                                     \
    bf16x8 afP = *reinterpret_cast<bf16x8*>(&aPw);                        \
    bf16x8 afN = *reinterpret_cast<bf16x8*>(&aNw);                        \
    MFM(afP, B0, aP0[HH]) MFM(afP, B1, aP1[HH]) MFM(afP, bones, aPs[HH])  \
    MFM(afN, B0, aN0[HH]) MFM(afN, B1, aN1[HH]) MFM(afN, bones, aNs[HH])  \
  }

#pragma unroll 1
  for (int t = 0; t < 32; ++t) {
    const int* a_ = adjr + t * 64;
    i32x4 a0 = *reinterpret_cast<const i32x4*>(a_);
    i32x4 a1 = *reinterpret_cast<const i32x4*>(a_ + 4);
    i32x4 a2 = *reinterpret_cast<const i32x4*>(a_ + 32);
    i32x4 a3 = *reinterpret_cast<const i32x4*>(a_ + 36);
    // adjacency halfword masks (adj in {0,1}: -v = all-ones or 0)
    u32x4 mkA, mkB;
#pragma unroll
    for (int p = 0; p < 2; ++p) {
      mkA[p] = __builtin_amdgcn_perm((u32)(-a0[2 * p + 1]), (u32)(-a0[2 * p]),
                                     0x05040100u);
      mkA[p + 2] = __builtin_amdgcn_perm((u32)(-a1[2 * p + 1]),
                                         (u32)(-a1[2 * p]), 0x05040100u);
      mkB[p] = __builtin_amdgcn_perm((u32)(-a2[2 * p + 1]), (u32)(-a2[2 * p]),
                                     0x05040100u);
      mkB[p + 2] = __builtin_amdgcn_perm((u32)(-a3[2 * p + 1]),
                                         (u32)(-a3[2 * p]), 0x05040100u);
    }
    size_t tb = (size_t)t * 512;   // table step per macro
    size_t pb = (size_t)t * 2048;  // panel step per macro (2 jt tiles)
#pragma unroll
    for (int hh = 0; hh < 2; ++hh) {
      float sv_ = hh ? sv1 : sv0;
      const char* d_ = dB + tb + hh * 128;
      const char* f1_ = f1B + tb + hh * 128;
      const char* f2_ = f2B + tb + hh * 128;
      const char* p0_ = pB + pb + (size_t)(hh * 2) * PS;
      const char* p1_ = p0_ + PS;
      {  // AF-a: j 0..31 of macro
        u32x4 Dv = *(const u32x4*)(d_);
        u32x4 F1v = *(const u32x4*)(f1_);
        u32x4 F2v = *(const u32x4*)(f2_);
        bf16x8 B0 = *(const bf16x8*)(p0_);
        bf16x8 B1 = *(const bf16x8*)(p1_);
        AFPLANE(hh, mkA, Dv, F1v, F2v, B0, B1, sv_)
      }
      {  // AF-b: j 32..63 (+64B in tables, +1024B panel tile)
        u32x4 Dv = *(const u32x4*)(d_ + 64);
        u32x4 F1v = *(const u32x4*)(f1_ + 64);
        u32x4 F2v = *(const u32x4*)(f2_ + 64);
        bf16x8 B0 = *(const bf16x8*)(p0_ + 1024);
        bf16x8 B1 = *(const bf16x8*)(p1_ + 1024);
        AFPLANE(hh, mkB, Dv, F1v, F2v, B0, B1, sv_)
      }
    }
  }
#undef AFPLANE
#undef MFM

  // epilogue: D layout col=lane&15 (o), row=(lane>>4)*4+reg (i).
  // Combine planes with E1/E2 here (once per output).
#pragma unroll
  for (int hh = 0; hh < 2; ++hh) {
    int hd = hd0 + hh;
    int rb = ibase + g * 4;
#pragma unroll
    for (int r = 0; r < 4; ++r) {
      int rowr = rb + r;
      float e1 = E1f[hd * N + rowr], e2 = E2f[hd * N + rowr];
      if (m == 0)
        plsum[(seg * NH + hd) * N + rowr] =
            e1 * aPs[hh][r] + e2 * aNs[hh][r];
      pacc[((size_t)seg * N + rowr) * 128 + hd * 32 + m] =
          e1 * aP0[hh][r] + e2 * aN0[hh][r];
      pacc[((size_t)seg * N + rowr) * 128 + hd * 32 + 16 + m] =
          e1 * aP1[hh][r] + e2 * aN1[hh][r];
    }
  }
}

// ---------------- k4: combine segments + normalize
__global__ __launch_bounds__(256, 2) void k4_combine(
    const float* __restrict__ pacc, const float* __restrict__ plsum,
    float* __restrict__ out) {
  int idx = blockIdx.x * 256 + threadIdx.x;
  int i = idx >> 7;
  int c = idx & 127;
  int hd = c >> 5;
  float a = 0.f, ls = 0.f;
#pragma unroll
  for (int s = 0; s < NSEG; ++s) {
    a += pacc[((size_t)s * NTOT + i) * 128 + c];
    ls += plsum[(s * NH + hd) * NTOT + i];
  }
  out[idx] = (ls > 0.f) ? a / ls : 0.f;
}

extern "C" void kernel_launch(void* const* d_in, const int* in_sizes, int n_in,
                              void* d_out, int out_size, void* d_ws,
                              size_t ws_size, hipStream_t stream) {
  const float* X = (const float*)d_in[0];
  const int* adj = (const int*)d_in[1];
  const float* W = (const float*)d_in[2];
  const float* a_src = (const float*)d_in[3];
  const float* a_dst = (const float*)d_in[4];
  float* out = (float*)d_out;

  char* ws = (char*)d_ws;
  float* h = (float*)(ws + 0x0);                              // 4 MB
  unsigned short* panel = (unsigned short*)(ws + 0x400000);   // 2 MB
  float* Sf = (float*)(ws + 0x600000);                        // 128 KB
  float* E1f = (float*)(ws + 0x620000);                       // 128 KB
  float* E2f = (float*)(ws + 0x640000);                       // 128 KB
  unsigned short* Dbf = (unsigned short*)(ws + 0x660000);     // 64 KB
  unsigned short* F1bf = (unsigned short*)(ws + 0x670000);    // 64 KB
  unsigned short* F2bf = (unsigned short*)(ws + 0x680000);    // 64 KB
  float* pacc = (float*)(ws + 0x700000);                      // 16 MB
  float* plsum = (float*)(ws + 0x1700000);                    // 512 KB

  k1_project<<<dim3(256), dim3(256), 0, stream>>>(X, W, h, panel);
  k2_scores<<<dim3(32), dim3(256), 0, stream>>>(h, a_src, a_dst, Sf, E1f, E2f,
                                                Dbf, F1bf, F2bf);
  k3_attn<<<dim3(256 * NSEG), dim3(256), 0, stream>>>(
      adj, Sf, E1f, E2f, Dbf, F1bf, F2bf, panel, pacc, plsum);
  k4_combine<<<dim3(4096), dim3(256), 0, stream>>>(pacc, plsum, out);
}